// Round 7
// baseline (281.851 us; speedup 1.0000x reference)
//
#include <hip/hip_runtime.h>
#include <cstdint>
#include <cstddef>

typedef short bf16x8 __attribute__((ext_vector_type(8)));
typedef unsigned short u16x4 __attribute__((ext_vector_type(4)));
typedef float f32x4  __attribute__((ext_vector_type(4)));
typedef unsigned short u16;

#define DEVI __device__ __forceinline__

constexpr int C     = 192;
constexpr int HEADS = 6;
constexpr int NQKV  = 576;   // 3*C
constexpr int HID   = 384;   // 2*C
constexpr int NTOK  = 131072;

DEVI u16 f2bf(float f){
  union { float f; unsigned u; } v; v.f = f;
  return (u16)((v.u + 0x7fffu + ((v.u >> 16) & 1u)) >> 16);
}

// exact-enough GELU: A&S 7.1.26 erf (max abs err 1.5e-7), branchless
DEVI float gelu(float xx){
  float y  = xx * 0.70710678118654752f;
  float ay = fabsf(y);
  float t  = __builtin_amdgcn_rcpf(1.0f + 0.3275911f * ay);
  float p  = t*(0.254829592f + t*(-0.284496736f + t*(1.421413741f + t*(-1.453152027f + t*1.061405429f))));
  float e  = __expf(-(y*y));
  float er = copysignf(1.0f - p*e, y);
  return 0.5f * xx * (1.0f + er);
}

// ---------------- prep: fragment-packed weights + packed bias table (SWAPPED layout) ----------------
__global__ void prep_kernel(const float* __restrict__ qkv_w,
                            const float* __restrict__ fc1_w,
                            const float* __restrict__ fc2_w,
                            const int*   __restrict__ rpi,
                            const float* __restrict__ rpb,
                            u16* __restrict__ qkvP,
                            u16* __restrict__ fc1P,
                            u16* __restrict__ fc2P,
                            float* __restrict__ bias_pk){
  int idx = blockIdx.x * blockDim.x + threadIdx.x;
  int stride = gridDim.x * blockDim.x;
  // qkvP: 36 panels x 6 ks
  for(int i = idx; i < 36*6*64*8; i += stride){
    int e = i & 7, lane = (i >> 3) & 63, t = i >> 9;
    int ks = t % 6, p = t / 6;
    int n = p*16 + (lane & 15), k = ks*32 + (lane >> 4)*8 + e;
    qkvP[i] = f2bf(qkv_w[k*NQKV + n]);
  }
  // fc1P: 24 panels x 6 ks
  for(int i = idx; i < 24*6*64*8; i += stride){
    int e = i & 7, lane = (i >> 3) & 63, t = i >> 9;
    int ks = t % 6, p = t / 6;
    int n = p*16 + (lane & 15), k = ks*32 + (lane >> 4)*8 + e;
    fc1P[i] = f2bf(fc1_w[k*HID + n]);
  }
  // fc2P: 12 panels x 12 ks
  for(int i = idx; i < 12*12*64*8; i += stride){
    int e = i & 7, lane = (i >> 3) & 63, t = i >> 9;
    int ks = t % 12, p = t / 12;
    int n = p*16 + (lane & 15), k = ks*32 + (lane >> 4)*8 + e;
    fc2P[i] = f2bf(fc2_w[k*C + n]);
  }
  // bias_pk (swapped-QK layout): [head][chunk5][nf2][mi4][lane64][r4]
  // value = bias[q = mi*16 + (lane&15)][kk = chunk*32 + nf*16 + (lane>>4)*4 + r]
  const int n4 = HEADS*5*2*4*64*4;
  for(int i = idx; i < n4; i += stride){
    int t = i;
    int r    = t & 3;  t >>= 2;
    int lane = t & 63; t >>= 6;
    int mi   = t & 3;  t >>= 2;
    int nf   = t & 1;  t >>= 1;
    int chunk = t % 5; int head = t / 5;
    int q  = mi*16 + (lane & 15);
    int kk = chunk*32 + nf*16 + ((lane >> 4) << 2) + r;
    float v = 0.f;
    if(kk < 144) v = rpb[rpi[q*144 + kk]*HEADS + head];
    bias_pk[i] = v;
  }
}

// ---------------- LN1 + QKV GEMM -> head-planar qkv bf16 [18 planes][131072][32] ----------------
__global__ __launch_bounds__(384, 4)
void qkv_kernel(const float* __restrict__ x,
                const float* __restrict__ g1,
                const float* __restrict__ b1,
                const u16* __restrict__ wP,
                const float* __restrict__ qb,
                u16* __restrict__ qkv){
  __shared__ u16 xn[64][200];
  __shared__ u16 rp[64][152];
  const int tid = threadIdx.x;
  const int bid = blockIdx.x;
  const int nh = (bid >> 3) & 1;
  const int tb = (bid & 7) + ((bid >> 4) << 3);
  const size_t tok0 = (size_t)tb * 64;
  if(tid < 256){
    const int trow = tid >> 2;
    const int j = tid & 3;
    const float* xr = x + (tok0 + trow)*C;
    float4 xv[12];
    #pragma unroll
    for(int u = 0; u < 12; ++u)
      xv[u] = *reinterpret_cast<const float4*>(xr + u*16 + j*4);
    float s1 = 0.f, s2 = 0.f;
    #pragma unroll
    for(int u = 0; u < 12; ++u){
      const float* f = reinterpret_cast<const float*>(&xv[u]);
      #pragma unroll
      for(int e = 0; e < 4; ++e){ s1 += f[e]; s2 += f[e]*f[e]; }
    }
    s1 += __shfl_xor(s1, 1, 64); s2 += __shfl_xor(s2, 1, 64);
    s1 += __shfl_xor(s1, 2, 64); s2 += __shfl_xor(s2, 2, 64);
    const float mean = s1 * (1.f/192.f);
    const float rstd = rsqrtf(s2*(1.f/192.f) - mean*mean + 1e-5f);
    #pragma unroll
    for(int u = 0; u < 12; ++u){
      const float4 gv = *reinterpret_cast<const float4*>(g1 + u*16 + j*4);
      const float4 bv = *reinterpret_cast<const float4*>(b1 + u*16 + j*4);
      const float* f = reinterpret_cast<const float*>(&xv[u]);
      const float* gp = reinterpret_cast<const float*>(&gv);
      const float* bp = reinterpret_cast<const float*>(&bv);
      u16x4 pk;
      #pragma unroll
      for(int e = 0; e < 4; ++e) pk[e] = f2bf((f[e] - mean)*rstd*gp[e] + bp[e]);
      *reinterpret_cast<u16x4*>(&xn[trow][u*16 + j*4]) = pk;
    }
  }
  __syncthreads();
  const int lane = tid & 63;
  const int wn = tid >> 6;
  const int g = lane >> 4, col = lane & 15;
  const f32x4 fzero = {0.f, 0.f, 0.f, 0.f};
  f32x4 acc[4][3];
  #pragma unroll
  for(int mi = 0; mi < 4; ++mi)
    #pragma unroll
    for(int nf = 0; nf < 3; ++nf) acc[mi][nf] = fzero;
  const int p0 = nh*18 + wn*3;
  #pragma unroll
  for(int ks = 0; ks < 6; ++ks){
    bf16x8 wf[3];
    #pragma unroll
    for(int nf = 0; nf < 3; ++nf)
      wf[nf] = *reinterpret_cast<const bf16x8*>(wP + ((size_t)(((p0 + nf)*6 + ks)*64) + lane)*8);
    bf16x8 a[4];
    #pragma unroll
    for(int mi = 0; mi < 4; ++mi)
      a[mi] = *reinterpret_cast<const bf16x8*>(&xn[mi*16 + col][ks*32 + g*8]);
    #pragma unroll
    for(int nf = 0; nf < 3; ++nf)
      #pragma unroll
      for(int mi = 0; mi < 4; ++mi)
        acc[mi][nf] = __builtin_amdgcn_mfma_f32_16x16x32_bf16(a[mi], wf[nf], acc[mi][nf], 0, 0, 0);
  }
  #pragma unroll
  for(int ph = 0; ph < 2; ++ph){
    if(wn >= ph*3 && wn < ph*3 + 3){
      const int wl = wn - ph*3;
      #pragma unroll
      for(int mi = 0; mi < 4; ++mi){
        #pragma unroll
        for(int nf = 0; nf < 3; ++nf){
          const int nloc = wl*48 + nf*16 + col;
          const float bb = qb[nh*288 + ph*144 + nloc];
          #pragma unroll
          for(int r = 0; r < 4; ++r)
            rp[mi*16 + g*4 + r][nloc] = f2bf(acc[mi][nf][r] + bb);
        }
      }
    }
    __syncthreads();
    #pragma unroll
    for(int it = 0; it < 3; ++it){
      const int c = tid + it*384;
      const int tok = c / 18, cc = c - tok*18;
      const int n0 = nh*288 + ph*144 + cc*8;
      const int pl = n0 >> 5, d0 = n0 & 31;
      bf16x8 vv = *reinterpret_cast<const bf16x8*>(&rp[tok][cc*8]);
      *reinterpret_cast<bf16x8*>(qkv + ((size_t)pl*NTOK + tok0 + tok)*32 + d0) = vv;
    }
    __syncthreads();
  }
}

// ---------------- windowed attention (no softmax): per (window, head), 4 waves ----------------
// Waves split the 64 q-rows (wave w owns q rows w*16..w*16+15). K in shared LDS (fragment layout),
// V^T in shared LDS, P wave-private rows of shared Pl. Swapped QK^T; integer-RNE P pack.
__global__ __launch_bounds__(256, 4)
void attn_kernel(const u16* __restrict__ qkv,   // [18][131072][32]
                 const float* __restrict__ bias_pk,
                 const float* __restrict__ x,
                 float* __restrict__ out){
  __shared__ u16 Kl[160][40];   // K rows x d=32 (row stride 80B, 16B-aligned)
  __shared__ u16 Vt[32][168];   // V^T: d x 160 (+pad)
  __shared__ u16 Pl[64][40];    // P chunk [q][kv_local] (+pad)
  const int tid  = threadIdx.x;
  const int lane = tid & 63;
  const int w    = tid >> 6;    // wave id = q-tile (mi)
  const int g = lane >> 4, col = lane & 15;
  const int win = blockIdx.x, head = blockIdx.y;
  const int bt = win >> 8, wh = (win >> 4) & 15, ww = win & 15;
  const int h0 = wh*8, w0 = ww*8;
  const size_t tokbase = (size_t)bt * 16384;
  const u16* Qp = qkv + (size_t)head      *NTOK*32;
  const u16* Kp = qkv + (size_t)(6 + head)*NTOK*32;
  const u16* Vp = qkv + (size_t)(12 + head)*NTOK*32;
  const bf16x8 z8 = {0,0,0,0,0,0,0,0};

  // ---- staging: waves split the 10 row-groups (w, w+4, w+8) ----
  #pragma unroll
  for(int ii = 0; ii < 3; ++ii){
    const int i = w + ii*4;
    if(i < 10){
      const int kr = i*16 + col;
      const int r12 = (kr*2731) >> 15;       // kr/12
      const int c12 = kr - r12*12;
      const int hh = h0 - 2 + r12;
      const int wp = w0 - 2 + c12;
      const bool valid = (kr < 144) && (hh >= 0) && (hh < 128) && (wp >= 0) && (wp < 128);
      const size_t t = valid ? (tokbase + (size_t)hh*128 + wp) : tokbase;
      bf16x8 kv_ = *reinterpret_cast<const bf16x8*>(Kp + t*32 + g*8);
      bf16x8 vv_ = *reinterpret_cast<const bf16x8*>(Vp + t*32 + g*8);
      kv_ = valid ? kv_ : z8;
      vv_ = valid ? vv_ : z8;
      *reinterpret_cast<bf16x8*>(&Kl[kr][g*8]) = kv_;
      #pragma unroll
      for(int e = 0; e < 8; ++e) Vt[g*8 + e][kr] = (u16)vv_[e];
    }
  }
  // Q fragment for this wave's q-tile
  bf16x8 qf;
  {
    const int row = w*16 + col;
    const size_t t = tokbase + (size_t)(h0 + (row >> 3))*128 + (w0 + (row & 7));
    qf = *reinterpret_cast<const bf16x8*>(Qp + t*32 + g*8);
  }
  __syncthreads();

  const f32x4 fzero = {0.f, 0.f, 0.f, 0.f};
  f32x4 oacc[2];
  oacc[0] = fzero; oacc[1] = fzero;
  const float scale = 0.17677669529663689f;  // 32^-0.5

  #pragma unroll
  for(int ch = 0; ch < 5; ++ch){
    // bias for this chunk / wave's q-tile
    float4 bv[2];
    #pragma unroll
    for(int nf = 0; nf < 2; ++nf)
      bv[nf] = *reinterpret_cast<const float4*>(
          bias_pk + (size_t)((((head*5 + ch)*2 + nf)*4 + w)*64 + lane)*4);
    // K fragments from shared LDS (identical across waves)
    bf16x8 kfr[2];
    #pragma unroll
    for(int nf = 0; nf < 2; ++nf)
      kfr[nf] = *reinterpret_cast<const bf16x8*>(&Kl[ch*32 + nf*16 + col][g*8]);
    // S^T = K·Q^T : lane holds S^T[kv = ch*32 + nf*16 + g*4 + r][q = w*16 + col]
    f32x4 st[2];
    #pragma unroll
    for(int nf = 0; nf < 2; ++nf)
      st[nf] = __builtin_amdgcn_mfma_f32_16x16x32_bf16(kfr[nf], qf, fzero, 0, 0, 0);
    // P = S^T*scale + bias -> bf16 (integer RNE) -> Pl (wave-private rows)
    #pragma unroll
    for(int nf = 0; nf < 2; ++nf){
      const float* bp = reinterpret_cast<const float*>(&bv[nf]);
      const float p0 = fmaf(st[nf][0], scale, bp[0]);
      const float p1 = fmaf(st[nf][1], scale, bp[1]);
      const float p2 = fmaf(st[nf][2], scale, bp[2]);
      const float p3 = fmaf(st[nf][3], scale, bp[3]);
      uint2 pw;
      pw.x = (unsigned)f2bf(p0) | ((unsigned)f2bf(p1) << 16);
      pw.y = (unsigned)f2bf(p2) | ((unsigned)f2bf(p3) << 16);
      *reinterpret_cast<uint2*>(
          reinterpret_cast<char*>(&Pl[0][0]) + (w*16 + col)*80 + nf*32 + g*8) = pw;
    }
    // P fragment (A): m = q (col within tile), k = kv_local = g*8+e
    bf16x8 pa = *reinterpret_cast<const bf16x8*>(
        reinterpret_cast<const char*>(&Pl[0][0]) + (w*16 + col)*80 + g*16);
    // V fragments (B): n = d, k = kv_local
    bf16x8 vfr[2];
    #pragma unroll
    for(int nf = 0; nf < 2; ++nf)
      vfr[nf] = *reinterpret_cast<const bf16x8*>(&Vt[nf*16 + col][ch*32 + g*8]);
    // O += P·V
    #pragma unroll
    for(int nf = 0; nf < 2; ++nf)
      oacc[nf] = __builtin_amdgcn_mfma_f32_16x16x32_bf16(pa, vfr[nf], oacc[nf], 0, 0, 0);
  }
  // epilogue: x1 = O + shortcut -> d_out (fp32)
  #pragma unroll
  for(int nf = 0; nf < 2; ++nf){
    #pragma unroll
    for(int r = 0; r < 4; ++r){
      const int row = w*16 + g*4 + r;
      const int hh = h0 + (row >> 3), wp = w0 + (row & 7);
      const size_t o = (tokbase + hh*128 + wp)*(size_t)C + head*32 + nf*16 + col;
      out[o] = oacc[nf][r] + x[o];
    }
  }
}

// ---------------- LN2 + FC1 + GELU + FC2 + residual, in-place on d_out ----------------
__global__ __launch_bounds__(512, 2)
void mlp_kernel(float* __restrict__ io,
                const float* __restrict__ g2,
                const float* __restrict__ b2,
                const u16* __restrict__ w1P,
                const float* __restrict__ fb1,
                const u16* __restrict__ w2P,
                const float* __restrict__ fb2){
  __shared__ u16 xn[64][200];
  __shared__ u16 hl[64][200];
  const int tid = threadIdx.x;
  const size_t tok0 = (size_t)blockIdx.x * 64;
  {
    const int trow = tid >> 3;
    const int j = tid & 7;
    const float* xr = io + (tok0 + trow)*C;
    float4 xv[6];
    #pragma unroll
    for(int u = 0; u < 6; ++u)
      xv[u] = *reinterpret_cast<const float4*>(xr + u*32 + j*4);
    float s1 = 0.f, s2 = 0.f;
    #pragma unroll
    for(int u = 0; u < 6; ++u){
      const float* f = reinterpret_cast<const float*>(&xv[u]);
      #pragma unroll
      for(int e = 0; e < 4; ++e){ s1 += f[e]; s2 += f[e]*f[e]; }
    }
    s1 += __shfl_xor(s1, 1, 64); s2 += __shfl_xor(s2, 1, 64);
    s1 += __shfl_xor(s1, 2, 64); s2 += __shfl_xor(s2, 2, 64);
    s1 += __shfl_xor(s1, 4, 64); s2 += __shfl_xor(s2, 4, 64);
    const float mean = s1 * (1.f/192.f);
    const float rstd = rsqrtf(s2*(1.f/192.f) - mean*mean + 1e-5f);
    #pragma unroll
    for(int u = 0; u < 6; ++u){
      const float4 gv = *reinterpret_cast<const float4*>(g2 + u*32 + j*4);
      const float4 bv = *reinterpret_cast<const float4*>(b2 + u*32 + j*4);
      const float* f = reinterpret_cast<const float*>(&xv[u]);
      const float* gp = reinterpret_cast<const float*>(&gv);
      const float* bp = reinterpret_cast<const float*>(&bv);
      u16x4 pk;
      #pragma unroll
      for(int e = 0; e < 4; ++e) pk[e] = f2bf((f[e] - mean)*rstd*gp[e] + bp[e]);
      *reinterpret_cast<u16x4*>(&xn[trow][u*32 + j*4]) = pk;
    }
  }
  __syncthreads();
  const int lane = tid & 63, wave = tid >> 6;
  const int wm = wave >> 2;
  const int wn = wave & 3;
  const int g = lane >> 4, col = lane & 15;
  const f32x4 fzero = {0.f, 0.f, 0.f, 0.f};
  f32x4 acc2[2][3];
  #pragma unroll
  for(int mi = 0; mi < 2; ++mi)
    #pragma unroll
    for(int nf = 0; nf < 3; ++nf) acc2[mi][nf] = fzero;
  #pragma unroll
  for(int hb = 0; hb < 2; ++hb){
    f32x4 acc1[2][3];
    #pragma unroll
    for(int mi = 0; mi < 2; ++mi)
      #pragma unroll
      for(int nf = 0; nf < 3; ++nf) acc1[mi][nf] = fzero;
    #pragma unroll
    for(int ks = 0; ks < 6; ++ks){
      bf16x8 wf[3];
      #pragma unroll
      for(int nf = 0; nf < 3; ++nf)
        wf[nf] = *reinterpret_cast<const bf16x8*>(w1P + ((size_t)(((hb*12 + wn*3 + nf)*6 + ks)*64) + lane)*8);
      bf16x8 a[2];
      #pragma unroll
      for(int mi = 0; mi < 2; ++mi)
        a[mi] = *reinterpret_cast<const bf16x8*>(&xn[wm*32 + mi*16 + col][ks*32 + g*8]);
      #pragma unroll
      for(int nf = 0; nf < 3; ++nf)
        #pragma unroll
        for(int mi = 0; mi < 2; ++mi)
          acc1[mi][nf] = __builtin_amdgcn_mfma_f32_16x16x32_bf16(a[mi], wf[nf], acc1[mi][nf], 0, 0, 0);
    }
    #pragma unroll
    for(int mi = 0; mi < 2; ++mi){
      #pragma unroll
      for(int nf = 0; nf < 3; ++nf){
        const int nl = wn*48 + nf*16 + col;
        const float bb = fb1[hb*192 + nl];
        #pragma unroll
        for(int r = 0; r < 4; ++r){
          const int row = wm*32 + mi*16 + g*4 + r;
          hl[row][nl] = f2bf(gelu(acc1[mi][nf][r] + bb));
        }
      }
    }
    __syncthreads();
    #pragma unroll
    for(int ks = 0; ks < 6; ++ks){
      bf16x8 wf[3];
      #pragma unroll
      for(int nf = 0; nf < 3; ++nf)
        wf[nf] = *reinterpret_cast<const bf16x8*>(w2P + ((size_t)(((wn*3 + nf)*12 + hb*6 + ks)*64) + lane)*8);
      bf16x8 a[2];
      #pragma unroll
      for(int mi = 0; mi < 2; ++mi)
        a[mi] = *reinterpret_cast<const bf16x8*>(&hl[wm*32 + mi*16 + col][ks*32 + g*8]);
      #pragma unroll
      for(int nf = 0; nf < 3; ++nf)
        #pragma unroll
        for(int mi = 0; mi < 2; ++mi)
          acc2[mi][nf] = __builtin_amdgcn_mfma_f32_16x16x32_bf16(a[mi], wf[nf], acc2[mi][nf], 0, 0, 0);
    }
    __syncthreads();
  }
  #pragma unroll
  for(int mi = 0; mi < 2; ++mi){
    #pragma unroll
    for(int nf = 0; nf < 3; ++nf){
      const int n = wn*48 + nf*16 + col;
      const float bb = fb2[n];
      #pragma unroll
      for(int r = 0; r < 4; ++r){
        const int row = wm*32 + mi*16 + g*4 + r;
        const size_t idx = (tok0 + row)*C + n;
        io[idx] = acc2[mi][nf][r] + bb + io[idx];
      }
    }
  }
}

extern "C" void kernel_launch(void* const* d_in, const int* in_sizes, int n_in,
                              void* d_out, int out_size, void* d_ws, size_t ws_size,
                              hipStream_t stream){
  const float* x    = (const float*)d_in[0];
  const int*   rpi  = (const int*)  d_in[2];
  const float* n1g  = (const float*)d_in[3];
  const float* n1b  = (const float*)d_in[4];
  const float* qkvw = (const float*)d_in[5];
  const float* qkvb = (const float*)d_in[6];
  const float* rpb  = (const float*)d_in[7];
  const float* n2g  = (const float*)d_in[8];
  const float* n2b  = (const float*)d_in[9];
  const float* fc1w = (const float*)d_in[10];
  const float* fc1b = (const float*)d_in[11];
  const float* fc2w = (const float*)d_in[12];
  const float* fc2b = (const float*)d_in[13];
  float* out = (float*)d_out;
  char* ws = (char*)d_ws;
  u16*   qkvP    = (u16*)  (ws + 0);
  u16*   fc1P    = (u16*)  (ws + 221184);
  u16*   fc2P    = (u16*)  (ws + 368640);
  float* bias_pk = (float*)(ws + 516096);
  u16*   qkvbuf  = (u16*)  (ws + 1499136);
  if(ws_size < 152494080ull) return;
  prep_kernel<<<dim3(512), dim3(256), 0, stream>>>(qkvw, fc1w, fc2w, rpi, rpb, qkvP, fc1P, fc2P, bias_pk);
  qkv_kernel<<<dim3(4096), dim3(384), 0, stream>>>(x, n1g, n1b, qkvP, qkvb, qkvbuf);
  attn_kernel<<<dim3(2048, 6), dim3(256), 0, stream>>>(qkvbuf, bias_pk, x, out);
  mlp_kernel<<<dim3(2048), dim3(512), 0, stream>>>(out, n2g, n2b, fc1P, fc1b, fc2P, fc2b);
}